// Round 9
// baseline (379.104 us; speedup 1.0000x reference)
//
#include <hip/hip_runtime.h>
#include <hip/hip_bf16.h>
#include <cstdint>
#include <cstddef>

typedef unsigned short ushort_t;
typedef __attribute__((ext_vector_type(8))) short short8;     // 8 bf16 = 4 VGPRs (MFMA A/B frag)
typedef __attribute__((ext_vector_type(8))) unsigned short ushort8;
typedef __attribute__((ext_vector_type(4))) unsigned short ushort4v;
typedef __attribute__((ext_vector_type(4))) float f32x4;

// Problem constants: B=2, L=2048, DIM=1024, H=16, dk=64
#define LPAD 72   // P LDS row stride (u16): 144 B -> b64 writes ~4-way max, b128 reads at floor

__device__ __forceinline__ unsigned short f2bf(float f) {
    unsigned int x = __float_as_uint(f);
    unsigned int r = x + 0x7fffu + ((x >> 16) & 1u);   // RNE
    return (unsigned short)(r >> 16);
}

// async global->LDS, 16 B per lane. LDS dest = wave-uniform base + lane*16 (m104 caveat).
__device__ __forceinline__ void async16(const ushort_t* g, ushort_t* l) {
    __builtin_amdgcn_global_load_lds(
        (const __attribute__((address_space(1))) unsigned int*)g,
        (__attribute__((address_space(3))) unsigned int*)l,
        16, 0, 0);
}

// fp32 -> bf16 pre-convert. z=0: q (scaled 1/8, exact), z=1: k, z=2: v; plus its weight.
__global__ __launch_bounds__(256) void cvt(const float* __restrict__ q,
                                           const float* __restrict__ k,
                                           const float* __restrict__ v,
                                           const float* __restrict__ Wq,
                                           const float* __restrict__ Wk,
                                           const float* __restrict__ Wv,
                                           ushort_t* __restrict__ qb,
                                           ushort_t* __restrict__ kb,
                                           ushort_t* __restrict__ vb,
                                           ushort_t* __restrict__ Wqb,
                                           ushort_t* __restrict__ Wkb,
                                           ushort_t* __restrict__ Wvb) {
    const int z = blockIdx.y;
    const float* X = (z == 0) ? q : (z == 1) ? k : v;
    const float* W = (z == 0) ? Wq : (z == 1) ? Wk : Wv;
    ushort_t* Xo = (z == 0) ? qb : (z == 1) ? kb : vb;
    ushort_t* Wo2 = (z == 0) ? Wqb : (z == 1) ? Wkb : Wvb;
    const size_t idx = (((size_t)blockIdx.x << 8) + threadIdx.x) << 3;
    const float* src; ushort_t* dst; float sc = 1.0f;
    if (idx < 4194304) { src = X + idx; dst = Xo + idx; if (z == 0) sc = 0.125f; }
    else               { src = W + (idx - 4194304); dst = Wo2 + (idx - 4194304); }
    f32x4 a0 = *(const f32x4*)src, a1 = *(const f32x4*)(src + 4);
    ushort8 o;
    #pragma unroll
    for (int j = 0; j < 4; j++) { o[j] = f2bf(a0[j] * sc); o[j + 4] = f2bf(a1[j] * sc); }
    *(ushort8*)dst = o;
}

// Pack mask (int32, nonzero = masked) into bits, tile-major:
// Mbits[(o/64)*4096 + (b*2048+i)] bit (o%64).
__global__ __launch_bounds__(256) void maskbits_kernel(const int* __restrict__ mask,
                                                       unsigned long long* __restrict__ Mbits) {
    const int row  = blockIdx.x;               // b*2048 + i
    const int w    = threadIdx.x >> 6;
    const int lane = threadIdx.x & 63;
    const int* mrow = mask + (size_t)row * 2048;
    #pragma unroll
    for (int it = 0; it < 8; it++) {
        const int o = (it << 8) + (w << 6) + lane;
        const unsigned long long bb = __ballot(mrow[o] != 0);
        if (lane == 0) Mbits[(size_t)((it << 2) + w) * 4096 + row] = bb;
    }
}

// WoH[j][k] = bf16(Wo[j][(k&63)*16 + (k>>6)]), k = h*64+d ordering.
__global__ __launch_bounds__(256) void woswz(const float* __restrict__ W,
                                             ushort_t* __restrict__ WoH) {
    __shared__ float row[1024 + 64];
    const int j = blockIdx.x, t = threadIdx.x;
    f32x4 v = *(const f32x4*)(W + (size_t)j * 1024 + (t << 2));
    #pragma unroll
    for (int s = 0; s < 4; s++) { const int c = (t << 2) + s; row[c + (c >> 4)] = v[s]; }
    __syncthreads();
    #pragma unroll
    for (int s = 0; s < 4; s++) {
        const int k = t + (s << 8);
        const int col = ((k & 63) << 4) + (k >> 6);
        WoH[(size_t)j * 1024 + k] = f2bf(row[col + (col >> 4)]);
    }
}

// Fused QKV projection v3: head-blocked tiles. Block = (z, head, 128 m-rows) x
// the head's full 64 d-columns (W rows j = head + 16*n). One block owns every
// output line it touches -> no partial-line write amplification.
// z=0: Qh[bh][l][d]; z=1: Kh[bh][l][d]; z=2: VhT[bh][d][l].
__global__ __launch_bounds__(256) void gemm_proj(const ushort_t* __restrict__ qb,
                                                 const ushort_t* __restrict__ kb,
                                                 const ushort_t* __restrict__ vb,
                                                 const ushort_t* __restrict__ Wqb,
                                                 const ushort_t* __restrict__ Wkb,
                                                 const ushort_t* __restrict__ Wvb,
                                                 ushort_t* __restrict__ Qh,
                                                 ushort_t* __restrict__ Kh,
                                                 ushort_t* __restrict__ VhT) {
    __shared__ ushort_t Xs[512 * 8];   // 8 KB: [c4(4)][128 rows][8]
    __shared__ ushort_t Ws[256 * 8];   // 4 KB: [c4(4)][64 rows][8]

    const int lid  = blockIdx.x;       // 0..1535
    const int z    = lid % 3;
    const int rem  = lid / 3;          // 0..511
    const int head = rem & 15;
    const int mIdx = rem >> 4;         // 0..31
    const int m0   = mIdx << 7;

    const ushort_t* Xb = (z == 0) ? qb : (z == 1) ? kb : vb;
    const ushort_t* Wb = (z == 0) ? Wqb : (z == 1) ? Wkb : Wvb;

    const int tid  = threadIdx.x;
    const int w    = tid >> 6;
    const int lane = tid & 63;
    const int lm   = lane & 15;
    const int quad = lane >> 4;
    const int wm   = w & 1;            // M half (64 rows)
    const int wn   = w >> 1;           // N half (32 of 64 d)

    f32x4 acc[4][2];
    #pragma unroll
    for (int i = 0; i < 4; i++)
        #pragma unroll
        for (int j = 0; j < 2; j++) acc[i][j] = (f32x4){0.f, 0.f, 0.f, 0.f};

    for (int k0 = 0; k0 < 1024; k0 += 32) {
        __syncthreads();
        #pragma unroll
        for (int i = 0; i < 2; i++) {      // X: 512 granules, 2 per wave
            const int L   = (((w << 1) + i) << 6) + lane;
            const int c4  = L >> 7, row = L & 127;
            async16(Xb + (size_t)(m0 + row) * 1024 + k0 + (c4 << 3),
                    &Xs[((((w << 1) + i) << 6) << 3)]);
        }
        {                                   // W: 256 granules, 1 per wave (c4=w, row=lane)
            const int j = head + (lane << 4);    // W channel for row n=lane
            async16(Wb + (size_t)j * 1024 + k0 + (w << 3), &Ws[((w << 6) << 3)]);
        }
        __syncthreads();
        short8 af[4], bf2[2];
        #pragma unroll
        for (int mf = 0; mf < 4; mf++)
            af[mf] = *(const short8*)&Xs[((quad << 7) + (wm << 6) + (mf << 4) + lm) << 3];
        #pragma unroll
        for (int nf = 0; nf < 2; nf++)
            bf2[nf] = *(const short8*)&Ws[((quad << 6) + (wn << 5) + (nf << 4) + lm) << 3];
        #pragma unroll
        for (int mf = 0; mf < 4; mf++)
            #pragma unroll
            for (int nf = 0; nf < 2; nf++)
                acc[mf][nf] = __builtin_amdgcn_mfma_f32_16x16x32_bf16(af[mf], bf2[nf], acc[mf][nf], 0, 0, 0);
    }

    // Stores: d = wn*32 + nf*16 + lm; l = l0 + wm*64 + mf*16 + quad*4 + r.
    const int bb = m0 >> 11;
    const int l0 = m0 & 2047;
    const size_t bh = (size_t)((bb << 4) + head);
    if (z != 2) {
        ushort_t* OUT = (z == 0) ? Qh : Kh;
        #pragma unroll
        for (int mf = 0; mf < 4; mf++)
            #pragma unroll
            for (int nf = 0; nf < 2; nf++) {
                const int d = (wn << 5) + (nf << 4) + lm;
                #pragma unroll
                for (int r = 0; r < 4; r++) {
                    const int l = l0 + (wm << 6) + (mf << 4) + (quad << 2) + r;
                    OUT[((bh * 2048 + l) << 6) + d] = f2bf(acc[mf][nf][r]);
                }
            }
    } else {
        #pragma unroll
        for (int mf = 0; mf < 4; mf++)
            #pragma unroll
            for (int nf = 0; nf < 2; nf++) {
                const int d = (wn << 5) + (nf << 4) + lm;
                const int l = l0 + (wm << 6) + (mf << 4) + (quad << 2);
                ushort4v o = { f2bf(acc[mf][nf][0]), f2bf(acc[mf][nf][1]),
                               f2bf(acc[mf][nf][2]), f2bf(acc[mf][nf][3]) };
                *(ushort4v*)(VhT + ((bh << 6) + d) * 2048 + l) = o;
            }
    }
}

// Output GEMM, 64x64 tile, global_load_lds staging (unchanged from round 8).
__global__ __launch_bounds__(256) void gemm_out(const ushort_t* __restrict__ mhaH,
                                                const ushort_t* __restrict__ WoH,
                                                float* __restrict__ C) {
    __shared__ ushort_t Xs[256 * 8];
    __shared__ ushort_t Ws[256 * 8];
    const int tid  = threadIdx.x;
    const int m0   = blockIdx.y << 6;
    const int n0   = blockIdx.x << 6;
    const int w    = tid >> 6;
    const int lane = tid & 63;
    const int lm   = lane & 15;
    const int quad = lane >> 4;
    const int ab   = m0 >> 11;
    const int al0  = m0 & 2047;

    f32x4 acc[4] = {{0.f,0.f,0.f,0.f},{0.f,0.f,0.f,0.f},{0.f,0.f,0.f,0.f},{0.f,0.f,0.f,0.f}};

    for (int k0 = 0; k0 < 1024; k0 += 32) {
        const int h  = k0 >> 6;
        const int d0 = k0 & 63;
        __syncthreads();
        async16(mhaH + (((size_t)(ab * 16 + h)) * 2048 + al0 + lane) * 64 + d0 + (w << 3),
                &Xs[(w << 6) << 3]);
        async16(WoH + (size_t)(n0 + lane) * 1024 + k0 + (w << 3),
                &Ws[(w << 6) << 3]);
        __syncthreads();
        short8 af = *(const short8*)&Xs[((quad << 6) + (w << 4) + lm) << 3];
        #pragma unroll
        for (int c = 0; c < 4; c++) {
            short8 bf = *(const short8*)&Ws[((quad << 6) + (c << 4) + lm) << 3];
            acc[c] = __builtin_amdgcn_mfma_f32_16x16x32_bf16(af, bf, acc[c], 0, 0, 0);
        }
    }
    #pragma unroll
    for (int c = 0; c < 4; c++) {
        #pragma unroll
        for (int r = 0; r < 4; r++) {
            const int row = m0 + (w << 4) + (quad << 2) + r;
            const int col = n0 + (c << 4) + lm;
            C[(size_t)row * 1024 + col] = acc[c][r];
        }
    }
}

// MFMA flash attention v4: S^T trick. S^T = mfma(A=K, B=Q) puts P per-lane as
// P[q=lm][key=16c+quad*4+r]: mask = 1 u64/lane, l accumulates per-lane, P->LDS
// is 4 b64/group, readback 2 b128. K/V frags load straight from global (L1/L2);
// NO barriers in the K-loop. LDS = P only (9.2 KB).
__global__ __launch_bounds__(256, 2) void flash_attn(const ushort_t* __restrict__ Qh,
                                                     const ushort_t* __restrict__ Kh,
                                                     const ushort_t* __restrict__ VhT,
                                                     const unsigned long long* __restrict__ Mbits,
                                                     ushort_t* __restrict__ mhaH) {
    __shared__ ushort_t Pw[4][16 * LPAD];

    const int tid  = threadIdx.x;
    const int w    = tid >> 6;
    const int lane = tid & 63;
    const int lm   = lane & 15;
    const int quad = lane >> 4;
    const int bh   = blockIdx.y;
    const int b    = bh >> 4;
    const int q0   = blockIdx.x << 7;

    const ushort_t* Qb  = Qh  + ((size_t)bh << 17);
    const ushort_t* Kb  = Kh  + ((size_t)bh << 17);
    const ushort_t* Vtb = VhT + ((size_t)bh << 17);   // [d][l]

    // Q B-frags: B[n=q=lm][k=dim quad*8+j], rows q0 + w*32 + g*16 + lm
    short8 bq[2][2];
    #pragma unroll
    for (int g = 0; g < 2; g++) {
        const ushort_t* qp = Qb + (size_t)(q0 + (w << 5) + (g << 4) + lm) * 64 + (quad << 3);
        bq[g][0] = *(const short8*)qp;
        bq[g][1] = *(const short8*)(qp + 32);
    }

    float l_part[2] = {0.f, 0.f};
    f32x4 o_acc[2][4] = {{{0.f,0.f,0.f,0.f},{0.f,0.f,0.f,0.f},{0.f,0.f,0.f,0.f},{0.f,0.f,0.f,0.f}},
                         {{0.f,0.f,0.f,0.f},{0.f,0.f,0.f,0.f},{0.f,0.f,0.f,0.f},{0.f,0.f,0.f,0.f}}};

    const int rowq = (b << 11) + q0 + (w << 5);

    for (int kt0 = 0; kt0 < 2048; kt0 += 64) {
        // K A-frags (A[m=key=lm][k=dim]) and V B-frags (B[n=d=lm][k=key]) from global
        short8 ak[4][2], bv[4][2];
        #pragma unroll
        for (int c = 0; c < 4; c++) {
            const ushort_t* kp = Kb + (size_t)(kt0 + (c << 4) + lm) * 64 + (quad << 3);
            ak[c][0] = *(const short8*)kp;
            ak[c][1] = *(const short8*)(kp + 32);
            const ushort_t* vp = Vtb + (size_t)((c << 4) + lm) * 2048 + kt0 + (quad << 3);
            bv[c][0] = *(const short8*)vp;
            bv[c][1] = *(const short8*)(vp + 32);
        }
        const unsigned long long* Mt = Mbits + ((size_t)(kt0 >> 6) << 12) + rowq;

        #pragma unroll
        for (int g = 0; g < 2; g++) {
            // S^T: lane holds S[q=g*16+lm][key=kt0+16c+quad*4+r]
            f32x4 s[4];
            #pragma unroll
            for (int c = 0; c < 4; c++) {
                f32x4 zz = {0.f, 0.f, 0.f, 0.f};
                zz = __builtin_amdgcn_mfma_f32_16x16x32_bf16(ak[c][0], bq[g][0], zz, 0, 0, 0);
                zz = __builtin_amdgcn_mfma_f32_16x16x32_bf16(ak[c][1], bq[g][1], zz, 0, 0, 0);
                s[c] = zz;
            }
            const unsigned long long M = Mt[(g << 4) + lm];   // this query's mask word
            float lsum = 0.f;
            #pragma unroll
            for (int c = 0; c < 4; c++) {
                #pragma unroll
                for (int r = 0; r < 4; r++) {
                    const unsigned bit = (unsigned)(M >> ((c << 4) + (quad << 2) + r)) & 1u;
                    const float p = bit ? 0.f : __expf(s[c][r]);
                    s[c][r] = p;
                    lsum += p;
                }
            }
            l_part[g] += lsum;
            // P -> LDS: row q=lm, keys 16c+quad*4..+3 as one b64 per c
            #pragma unroll
            for (int c = 0; c < 4; c++) {
                ushort4v pk = { f2bf(s[c][0]), f2bf(s[c][1]), f2bf(s[c][2]), f2bf(s[c][3]) };
                *(ushort4v*)&Pw[w][lm * LPAD + (c << 4) + (quad << 2)] = pk;
            }
            // P A-frag readback (same-wave RAW; compiler inserts lgkmcnt)
            short8 ap0 = *(const short8*)&Pw[w][lm * LPAD + (quad << 3)];
            short8 ap1 = *(const short8*)&Pw[w][lm * LPAD + 32 + (quad << 3)];
            #pragma unroll
            for (int cd = 0; cd < 4; cd++) {
                o_acc[g][cd] = __builtin_amdgcn_mfma_f32_16x16x32_bf16(ap0, bv[cd][0], o_acc[g][cd], 0, 0, 0);
                o_acc[g][cd] = __builtin_amdgcn_mfma_f32_16x16x32_bf16(ap1, bv[cd][1], o_acc[g][cd], 0, 0, 0);
            }
        }
    }

    // epilogue: l lives per-lane (query lm); reduce across quads, then shfl to rows
    #pragma unroll
    for (int g = 0; g < 2; g++) {
        float l = l_part[g];
        l += __shfl_xor(l, 16, 64);
        l += __shfl_xor(l, 32, 64);
        const float invl = 1.0f / l;
        #pragma unroll
        for (int r = 0; r < 4; r++) {
            const float il = __shfl(invl, (quad << 2) + r, 64);   // inv_l for query quad*4+r
            const int i = q0 + (w << 5) + (g << 4) + (quad << 2) + r;
            ushort_t* orow = mhaH + (((size_t)bh * 2048 + i) << 6);
            #pragma unroll
            for (int cd = 0; cd < 4; cd++)
                orow[(cd << 4) + lm] = f2bf(o_acc[g][cd][r] * il);
        }
    }
}

extern "C" void kernel_launch(void* const* d_in, const int* in_sizes, int n_in,
                              void* d_out, int out_size, void* d_ws, size_t ws_size,
                              hipStream_t stream) {
    const float* q    = (const float*)d_in[0];
    const float* k    = (const float*)d_in[1];
    const float* v    = (const float*)d_in[2];
    const int*   mask = (const int*)d_in[3];
    const float* Wq   = (const float*)d_in[4];
    const float* Wk   = (const float*)d_in[5];
    const float* Wv   = (const float*)d_in[6];
    const float* Wo   = (const float*)d_in[7];
    float* out = (float*)d_out;

    // ws plan (u16 units): qb kb vb (4M) | Wqb Wkb Wvb (1M) | Qh Kh VhT (4M) = 27M u16 = 54 MB
    // mhaH aliases qb; WoH + Mbits alias kb (both dead after gemm_proj).
    ushort_t* qb   = (ushort_t*)d_ws;
    ushort_t* kb   = qb  + 4194304;
    ushort_t* vb   = kb  + 4194304;
    ushort_t* Wqb  = vb  + 4194304;
    ushort_t* Wkb  = Wqb + 1048576;
    ushort_t* Wvb  = Wkb + 1048576;
    ushort_t* Qh   = Wvb + 1048576;
    ushort_t* Kh   = Qh  + 4194304;
    ushort_t* VhT  = Kh  + 4194304;
    ushort_t* mhaH = qb;
    ushort_t* WoH  = kb;
    unsigned long long* Mbits = (unsigned long long*)(kb + 1048576);

    dim3 gb(256);
    cvt<<<dim3(2560, 3), gb, 0, stream>>>(q, k, v, Wq, Wk, Wv, qb, kb, vb, Wqb, Wkb, Wvb);
    gemm_proj<<<dim3(1536), gb, 0, stream>>>(qb, kb, vb, Wqb, Wkb, Wvb, Qh, Kh, VhT);
    maskbits_kernel<<<dim3(4096), gb, 0, stream>>>(mask, Mbits);
    woswz<<<dim3(1024), gb, 0, stream>>>(Wo, WoH);
    flash_attn<<<dim3(16, 32), gb, 0, stream>>>(Qh, Kh, VhT, Mbits, mhaH);
    gemm_out<<<dim3(16, 64), gb, 0, stream>>>(mhaH, WoH, out);
}